// Round 4
// baseline (293.942 us; speedup 1.0000x reference)
//
#include <hip/hip_runtime.h>
#include <math.h>

#define LMAX  32768
#define WWIN  1024
#define KFIR  128
#define TO    1024               // outputs per block (tile)
#define WOUT  256                // outputs per wave (wave-autonomous sub-tile)
#define HALO  128
#define SEGW  (WOUT + HALO)      // 384 staged samples per wave
#define NMAX  1024               // max notes

// ---------------- per-note parameter kernel ----------------
// Weights staged in LDS once per block; fully-unrolled register MLP.
__global__ __launch_bounds__(256) void params_k(
    const float* __restrict__ freq, const float* __restrict__ velo,
    const float* __restrict__ w1,  const float* __restrict__ b1,
    const float* __restrict__ w2,  const float* __restrict__ b2,
    const float* __restrict__ ws1, const float* __restrict__ bs1,
    const float* __restrict__ ws2, const float* __restrict__ bs2,
    const int* __restrict__ starts, const int* __restrict__ lengths,
    int Dn, int N,
    float* __restrict__ amps_out, int* __restrict__ outlen_out,
    float* __restrict__ veln_out)
{
    __shared__ float s_w1[32], s_b1[32], s_w2[64], s_b2[2];
    __shared__ float s_ws1[256], s_bs1[64], s_ws2[512], s_bs2[8];

    const int tid = threadIdx.x;
    if (tid < 32)  { s_w1[tid] = w1[tid]; s_b1[tid] = b1[tid]; }
    if (tid < 64)  { s_w2[tid] = w2[tid]; s_bs1[tid] = bs1[tid]; }
    if (tid < 2)   s_b2[tid] = b2[tid];
    if (tid < 8)   s_bs2[tid] = bs2[tid];
    s_ws1[tid] = ws1[tid];                       // 256 elements
    s_ws2[tid] = ws2[tid];
    s_ws2[tid + 256] = ws2[tid + 256];           // 512 elements
    __syncthreads();

    const int n = blockIdx.x * blockDim.x + tid;
    if (n >= N) return;

    int st  = starts[n];
    int len = lengths[n];
    int ol  = min(st + len, Dn) - st;
    ol = max(0, min(ol, LMAX));
    outlen_out[n] = ol;

    float v = velo[n] * (1.0f / 127.0f);
    veln_out[n] = v;

    float nt = (float)st / (float)Dn;

    // time latent: 1 -> 32 -> 2
    float lat0 = s_b2[0], lat1 = s_b2[1];
    #pragma unroll
    for (int j = 0; j < 32; ++j) {
        float h = fmaxf(fmaf(nt, s_w1[j], s_b1[j]), 0.0f);
        lat0 = fmaf(h, s_w2[j * 2 + 0], lat0);
        lat1 = fmaf(h, s_w2[j * 2 + 1], lat1);
    }

    const float f0 = freq[n], f1 = v, f2 = lat0, f3 = lat1;

    // synth MLP: 4 -> 64 -> 8 (softplus), register acc tile
    float acc[8];
    #pragma unroll
    for (int h = 0; h < 8; ++h) acc[h] = s_bs2[h];
    #pragma unroll
    for (int j = 0; j < 64; ++j) {
        float a = s_bs1[j];
        a = fmaf(f0, s_ws1[0 * 64 + j], a);
        a = fmaf(f1, s_ws1[1 * 64 + j], a);
        a = fmaf(f2, s_ws1[2 * 64 + j], a);
        a = fmaf(f3, s_ws1[3 * 64 + j], a);
        a = fmaxf(a, 0.0f);
        #pragma unroll
        for (int h = 0; h < 8; ++h)
            acc[h] = fmaf(a, s_ws2[j * 8 + h], acc[h]);
    }
    #pragma unroll
    for (int h = 0; h < 8; ++h) {
        float a = acc[h];
        float sp = fmaxf(a, 0.0f) + log1pf(expf(-fabsf(a)));
        amps_out[n * 8 + h] = sp;
    }
}

__device__ __forceinline__ float fast_tanh(float x) {
    // tanh(x) = 1 - 2/(exp(2x)+1); exp via v_exp_f32 (exp2)
    float e = __builtin_amdgcn_exp2f(x * 2.8853900817779268f);  // 2*log2(e)
    return fmaf(-2.0f, __builtin_amdgcn_rcpf(e + 1.0f), 1.0f);
}

// ---------------- gather synthesis kernel (wave-autonomous) ----------------
// grid: ceil(Dn/TO) blocks, 256 threads = 4 waves.
// Each wave independently owns WOUT consecutive outputs + private LDS slice;
// note list built once per block, then NO barriers in the pair loop.
__global__ __launch_bounds__(256, 4) void synth_gather_k(
    const float* __restrict__ freq_g, const int* __restrict__ starts,
    const float* __restrict__ amps_g, const int* __restrict__ outlen_g,
    const float* __restrict__ veln_g, const float* __restrict__ fir,
    float* __restrict__ out, int Dn, int N)
{
    __shared__ __align__(16) float seg[4][SEGW];
    __shared__ __align__(16) float fir_s[KFIR];
    __shared__ unsigned short note_list[NMAX];
    __shared__ int note_cnt;

    const int tid  = threadIdx.x;
    const int wid  = tid >> 6;
    const int lane = tid & 63;
    const int o0   = blockIdx.x * TO;         // first output of this tile
    const int o_end = min(o0 + TO, Dn);
    const int ow   = o0 + wid * WOUT;         // this wave's first output

    if (tid < KFIR) fir_s[tid] = fir[tid];
    if (tid == 0) note_cnt = 0;
    __syncthreads();
    for (int j = tid; j < N; j += 256) {
        int st = starts[j];
        int ol = outlen_g[j];
        if (st < o_end && st + ol > o0) {
            int p = atomicAdd(&note_cnt, 1);
            note_list[p] = (unsigned short)j;
        }
    }
    __syncthreads();
    const int K = note_cnt;

    float* __restrict__ segw = seg[wid];
    const int a = lane * 4;                   // per-lane LDS base / wave-local output
    float acc0 = 0.0f, acc1 = 0.0f, acc2 = 0.0f, acc3 = 0.0f;

    const double inv2pi = 0.15915494309189535;

    for (int kk = 0; kk < K; ++kk) {
        const int nid = __builtin_amdgcn_readfirstlane((int)note_list[kk]);
        const int st  = starts[nid];
        const int ol  = outlen_g[nid];
        const int base = ow - st;             // note-local index of wave's first output
        // wave-uniform skip: note doesn't touch this wave's window
        if (base >= ol || base + WOUT <= 0) continue;

        const float f = freq_g[nid];
        const float v = veln_g[nid];
        const float* an = amps_g + nid * 8;
        const float A0 = an[0], A1 = an[1], A2 = an[2], A3 = an[3];
        const float A4 = an[4], A5 = an[5], A6 = an[6], A7 = an[7];
        const double fd = (double)f;

        // per-thread phase seed (one f64 reduction per pair), then fp32 stepping
        const int t0 = base - HALO + lane;
        double rev0 = fd * (double)t0 * inv2pi;
        float r = (float)(rev0 - floor(rev0));            // [0,1) revolutions
        double s64d = fd * 64.0 * inv2pi;
        const float s64 = (float)(s64d - floor(s64d));    // frac(step per 64 samples)
        const int wbase = ol - WWIN;

        // ---- stage this wave's SEGW samples (no cross-wave sync needed) ----
        #pragma unroll
        for (int i = 0; i < 6; ++i) {
            int t = t0 + 64 * i;
            float val = 0.0f;
            if (t >= 0 && t < ol) {
                float s1 = __builtin_amdgcn_sinf(r);
                float c1 = __builtin_amdgcn_cosf(r);
                float tc = c1 + c1;
                float sA = s1;
                float sum = A0 * sA;
                float sB = tc * sA;              sum = fmaf(A1, sB, sum);
                float sC = fmaf(tc, sB, -sA);    sum = fmaf(A2, sC, sum);
                float sD = fmaf(tc, sC, -sB);    sum = fmaf(A3, sD, sum);
                float sE = fmaf(tc, sD, -sC);    sum = fmaf(A4, sE, sum);
                float sF = fmaf(tc, sE, -sD);    sum = fmaf(A5, sF, sum);
                float sG = fmaf(tc, sF, -sE);    sum = fmaf(A6, sG, sum);
                float sH = fmaf(tc, sG, -sF);    sum = fmaf(A7, sH, sum);
                int wpos = t - wbase;
                float factor = 1.0f;
                if (wpos >= 0)
                    factor = 0.5f - 0.5f * __builtin_amdgcn_cosf((float)wpos * (1.0f / WWIN));
                val = v * sum * factor;
            }
            segw[lane + 64 * i] = val;
            r += s64;
            r -= (r >= 1.0f) ? 1.0f : 0.0f;
        }
        // (compiler inserts lgkmcnt wait: same-wave write->read dependence on segw)

        // ---- 128-tap FIR, 4 outputs/lane, sliding register window ----
        const int t_out = base + a;           // note-local index of output a
        if (t_out + 3 >= 0 && t_out < ol) {
            float w1r, w2r, w3r, w4r, w5r, w6r, w7r;
            {
                float4 cur = *(const float4*)&segw[a];
                w1r = cur.y; w2r = cur.z; w3r = cur.w;
            }
            float y0 = 0.0f, y1 = 0.0f, y2 = 0.0f, y3 = 0.0f;
            #pragma unroll
            for (int m = 0; m < 32; ++m) {
                float4 tv  = *(const float4*)&fir_s[4 * m];        // uniform broadcast
                float4 nxt = *(const float4*)&segw[a + 4 * m + 4]; // contiguous b128
                w4r = nxt.x; w5r = nxt.y; w6r = nxt.z; w7r = nxt.w;
                y0 = fmaf(tv.x, w1r, y0); y1 = fmaf(tv.x, w2r, y1);
                y2 = fmaf(tv.x, w3r, y2); y3 = fmaf(tv.x, w4r, y3);
                y0 = fmaf(tv.y, w2r, y0); y1 = fmaf(tv.y, w3r, y1);
                y2 = fmaf(tv.y, w4r, y2); y3 = fmaf(tv.y, w5r, y3);
                y0 = fmaf(tv.z, w3r, y0); y1 = fmaf(tv.z, w4r, y1);
                y2 = fmaf(tv.z, w5r, y2); y3 = fmaf(tv.z, w6r, y3);
                y0 = fmaf(tv.w, w4r, y0); y1 = fmaf(tv.w, w5r, y1);
                y2 = fmaf(tv.w, w6r, y2); y3 = fmaf(tv.w, w7r, y3);
                w1r = w5r; w2r = w6r; w3r = w7r;
            }

            // ---- tanh + masked accumulate (register, no atomics) ----
            if (t_out + 0 >= 0 && t_out + 0 < ol) acc0 += fast_tanh(y0);
            if (t_out + 1 >= 0 && t_out + 1 < ol) acc1 += fast_tanh(y1);
            if (t_out + 2 >= 0 && t_out + 2 < ol) acc2 += fast_tanh(y2);
            if (t_out + 3 >= 0 && t_out + 3 < ol) acc3 += fast_tanh(y3);
        }
    }

    // ---- single coalesced store per output ----
    const int o = ow + a;
    if (o + 3 < Dn) {
        *(float4*)&out[o] = make_float4(acc0, acc1, acc2, acc3);
    } else {
        if (o + 0 < Dn) out[o + 0] = acc0;
        if (o + 1 < Dn) out[o + 1] = acc1;
        if (o + 2 < Dn) out[o + 2] = acc2;
        if (o + 3 < Dn) out[o + 3] = acc3;
    }
}

// ---------------- launcher ----------------
extern "C" void kernel_launch(void* const* d_in, const int* in_sizes, int n_in,
                              void* d_out, int out_size, void* d_ws, size_t ws_size,
                              hipStream_t stream) {
    const float* freq    = (const float*)d_in[0];
    const float* velo    = (const float*)d_in[1];
    const float* w1      = (const float*)d_in[2];
    const float* b1      = (const float*)d_in[3];
    const float* w2      = (const float*)d_in[4];
    const float* b2      = (const float*)d_in[5];
    const float* ws1     = (const float*)d_in[6];
    const float* bs1     = (const float*)d_in[7];
    const float* ws2     = (const float*)d_in[8];
    const float* bs2     = (const float*)d_in[9];
    const float* fir     = (const float*)d_in[10];
    const int*   starts  = (const int*)d_in[11];
    const int*   lengths = (const int*)d_in[12];

    const int N  = in_sizes[0];
    const int Dn = out_size;
    float* out = (float*)d_out;

    // workspace layout: amps[N*8] | outlen[N] | veln[N]
    float* amps   = (float*)d_ws;
    int*   outlen = (int*)((char*)d_ws + (size_t)N * 8 * sizeof(float));
    float* veln   = (float*)((char*)d_ws + (size_t)N * 8 * sizeof(float) + (size_t)N * sizeof(int));

    params_k<<<(N + 255) / 256, 256, 0, stream>>>(
        freq, velo, w1, b1, w2, b2, ws1, bs1, ws2, bs2,
        starts, lengths, Dn, N, amps, outlen, veln);

    int n_tiles = (Dn + TO - 1) / TO;
    synth_gather_k<<<n_tiles, 256, 0, stream>>>(
        freq, starts, amps, outlen, veln, fir, out, Dn, N);
}

// Round 5
// 278.559 us; speedup vs baseline: 1.0552x; 1.0552x over previous
//
#include <hip/hip_runtime.h>
#include <math.h>

#define LMAX  32768
#define WWIN  1024
#define KFIR  128
#define WOUT  512                // outputs per wave (two 256-chunks per lane)
#define HALF  256
#define TO    1024               // outputs per block (2 waves)
#define HALO  128
#define SEGW  640                // 512 + 128 staged samples per wave
#define SEGP  648                // padded
#define NMAX  1024               // max notes

// ---------------- per-note parameter kernel ----------------
__global__ __launch_bounds__(256) void params_k(
    const float* __restrict__ freq, const float* __restrict__ velo,
    const float* __restrict__ w1,  const float* __restrict__ b1,
    const float* __restrict__ w2,  const float* __restrict__ b2,
    const float* __restrict__ ws1, const float* __restrict__ bs1,
    const float* __restrict__ ws2, const float* __restrict__ bs2,
    const int* __restrict__ starts, const int* __restrict__ lengths,
    int Dn, int N,
    float* __restrict__ amps_out, int* __restrict__ outlen_out,
    float* __restrict__ veln_out)
{
    __shared__ float s_w1[32], s_b1[32], s_w2[64], s_b2[2];
    __shared__ float s_ws1[256], s_bs1[64], s_ws2[512], s_bs2[8];

    const int tid = threadIdx.x;
    if (tid < 32)  { s_w1[tid] = w1[tid]; s_b1[tid] = b1[tid]; }
    if (tid < 64)  { s_w2[tid] = w2[tid]; s_bs1[tid] = bs1[tid]; }
    if (tid < 2)   s_b2[tid] = b2[tid];
    if (tid < 8)   s_bs2[tid] = bs2[tid];
    s_ws1[tid] = ws1[tid];
    s_ws2[tid] = ws2[tid];
    s_ws2[tid + 256] = ws2[tid + 256];
    __syncthreads();

    const int n = blockIdx.x * blockDim.x + tid;
    if (n >= N) return;

    int st  = starts[n];
    int len = lengths[n];
    int ol  = min(st + len, Dn) - st;
    ol = max(0, min(ol, LMAX));
    outlen_out[n] = ol;

    float v = velo[n] * (1.0f / 127.0f);
    veln_out[n] = v;

    float nt = (float)st / (float)Dn;

    float lat0 = s_b2[0], lat1 = s_b2[1];
    #pragma unroll
    for (int j = 0; j < 32; ++j) {
        float h = fmaxf(fmaf(nt, s_w1[j], s_b1[j]), 0.0f);
        lat0 = fmaf(h, s_w2[j * 2 + 0], lat0);
        lat1 = fmaf(h, s_w2[j * 2 + 1], lat1);
    }

    const float f0 = freq[n], f1 = v, f2 = lat0, f3 = lat1;

    float acc[8];
    #pragma unroll
    for (int h = 0; h < 8; ++h) acc[h] = s_bs2[h];
    #pragma unroll
    for (int j = 0; j < 64; ++j) {
        float a = s_bs1[j];
        a = fmaf(f0, s_ws1[0 * 64 + j], a);
        a = fmaf(f1, s_ws1[1 * 64 + j], a);
        a = fmaf(f2, s_ws1[2 * 64 + j], a);
        a = fmaf(f3, s_ws1[3 * 64 + j], a);
        a = fmaxf(a, 0.0f);
        #pragma unroll
        for (int h = 0; h < 8; ++h)
            acc[h] = fmaf(a, s_ws2[j * 8 + h], acc[h]);
    }
    #pragma unroll
    for (int h = 0; h < 8; ++h) {
        float a = acc[h];
        float sp = fmaxf(a, 0.0f) + log1pf(expf(-fabsf(a)));
        amps_out[n * 8 + h] = sp;
    }
}

__device__ __forceinline__ float fast_tanh(float x) {
    float e = __builtin_amdgcn_exp2f(x * 2.8853900817779268f);  // 2*log2(e)
    return fmaf(-2.0f, __builtin_amdgcn_rcpf(e + 1.0f), 1.0f);
}

// ---------------- gather synthesis kernel (2 waves, dual-chunk) ----------------
// grid: ceil(Dn/TO) blocks, 128 threads = 2 waves.
// Each wave owns WOUT=512 outputs as two 256-chunks per lane; private LDS slice.
// Note list built once per block (one barrier); no barriers in the pair loop.
__global__ __launch_bounds__(128, 4) void synth_gather_k(
    const float* __restrict__ freq_g, const int* __restrict__ starts,
    const float* __restrict__ amps_g, const int* __restrict__ outlen_g,
    const float* __restrict__ veln_g, const float* __restrict__ fir,
    float* __restrict__ out, int Dn, int N)
{
    __shared__ __align__(16) float seg[2][SEGP];
    __shared__ __align__(16) float fir_s[KFIR];
    __shared__ unsigned short note_list[NMAX];
    __shared__ int note_cnt;

    const int tid  = threadIdx.x;
    const int wid  = tid >> 6;
    const int lane = tid & 63;
    const int o0   = blockIdx.x * TO;
    const int o_end = min(o0 + TO, Dn);
    const int ow   = o0 + wid * WOUT;         // this wave's first output

    fir_s[tid] = fir[tid];                    // 128 threads, 128 taps
    if (tid == 0) note_cnt = 0;
    __syncthreads();
    for (int j = tid; j < N; j += 128) {
        int st = starts[j];
        int ol = outlen_g[j];
        if (st < o_end && st + ol > o0) {
            int p = atomicAdd(&note_cnt, 1);
            note_list[p] = (unsigned short)j;
        }
    }
    __syncthreads();
    const int K = note_cnt;

    float* __restrict__ segw = seg[wid];
    const int aA = lane * 4;                  // chunk A base (LDS & wave-local out)
    const int aB = aA + HALF;                 // chunk B base
    float accA0 = 0.f, accA1 = 0.f, accA2 = 0.f, accA3 = 0.f;
    float accB0 = 0.f, accB1 = 0.f, accB2 = 0.f, accB3 = 0.f;

    const double inv2pi = 0.15915494309189535;

    for (int kk = 0; kk < K; ++kk) {
        const int nid = __builtin_amdgcn_readfirstlane((int)note_list[kk]);
        const int st  = starts[nid];
        const int ol  = outlen_g[nid];
        const int base = ow - st;             // note-local index of wave's first output
        if (base >= ol || base + WOUT <= 0) continue;   // wave-uniform skip

        const float f = freq_g[nid];
        const float v = veln_g[nid];
        const float* an = amps_g + nid * 8;
        const float A0 = an[0], A1 = an[1], A2 = an[2], A3 = an[3];
        const float A4 = an[4], A5 = an[5], A6 = an[6], A7 = an[7];
        const double fd = (double)f;

        // phase seed (f64 once per pair) + fixed-angle rotation stepping (64 samples)
        const int tseed = base - HALO + lane;
        double rev0 = fd * (double)tseed * inv2pi;
        float r0 = (float)(rev0 - floor(rev0));
        float s = __builtin_amdgcn_sinf(r0);
        float c = __builtin_amdgcn_cosf(r0);
        double d64 = fd * 64.0 * inv2pi;
        float r64 = (float)(d64 - floor(d64));
        const float sd = __builtin_amdgcn_sinf(r64);
        const float cd = __builtin_amdgcn_cosf(r64);
        const int wbase = ol - WWIN;

        // ---- stage SEGW samples (same-wave, no barrier) ----
        #pragma unroll
        for (int i = 0; i < 10; ++i) {
            int t = tseed + 64 * i;
            float val = 0.0f;
            if (t >= 0 && t < ol) {
                float tc = c + c;
                float sA = s;
                float sum = A0 * sA;
                float sB = tc * sA;              sum = fmaf(A1, sB, sum);
                float sC = fmaf(tc, sB, -sA);    sum = fmaf(A2, sC, sum);
                float sD = fmaf(tc, sC, -sB);    sum = fmaf(A3, sD, sum);
                float sE = fmaf(tc, sD, -sC);    sum = fmaf(A4, sE, sum);
                float sF = fmaf(tc, sE, -sD);    sum = fmaf(A5, sF, sum);
                float sG = fmaf(tc, sF, -sE);    sum = fmaf(A6, sG, sum);
                float sH = fmaf(tc, sG, -sF);    sum = fmaf(A7, sH, sum);
                int wpos = t - wbase;
                float factor = 1.0f;
                if (wpos >= 0)
                    factor = 0.5f - 0.5f * __builtin_amdgcn_cosf((float)wpos * (1.0f / WWIN));
                val = v * sum * factor;
            }
            segw[lane + 64 * i] = val;
            // rotate (s,c) by the 64-sample angle
            float ns = fmaf(s, cd, c * sd);
            float nc = fmaf(c, cd, -(s * sd));
            s = ns; c = nc;
        }

        // ---- 128-tap FIR: two sliding windows, 8 outputs/lane ----
        float wA1, wA2, wA3, wB1, wB2, wB3;
        {
            float4 cA = *(const float4*)&segw[aA];
            float4 cB = *(const float4*)&segw[aB];
            wA1 = cA.y; wA2 = cA.z; wA3 = cA.w;
            wB1 = cB.y; wB2 = cB.z; wB3 = cB.w;
        }
        float yA0 = 0.f, yA1 = 0.f, yA2 = 0.f, yA3 = 0.f;
        float yB0 = 0.f, yB1 = 0.f, yB2 = 0.f, yB3 = 0.f;
        #pragma unroll
        for (int m = 0; m < 32; ++m) {
            float t0 = fir_s[4 * m + 0];      // uniform b32 broadcasts
            float t1 = fir_s[4 * m + 1];
            float t2 = fir_s[4 * m + 2];
            float t3 = fir_s[4 * m + 3];
            float4 nA = *(const float4*)&segw[aA + 4 * m + 4];
            float4 nB = *(const float4*)&segw[aB + 4 * m + 4];
            float wA4 = nA.x, wA5 = nA.y, wA6 = nA.z, wA7 = nA.w;
            float wB4 = nB.x, wB5 = nB.y, wB6 = nB.z, wB7 = nB.w;
            yA0 = fmaf(t0, wA1, yA0); yA1 = fmaf(t0, wA2, yA1);
            yA2 = fmaf(t0, wA3, yA2); yA3 = fmaf(t0, wA4, yA3);
            yB0 = fmaf(t0, wB1, yB0); yB1 = fmaf(t0, wB2, yB1);
            yB2 = fmaf(t0, wB3, yB2); yB3 = fmaf(t0, wB4, yB3);
            yA0 = fmaf(t1, wA2, yA0); yA1 = fmaf(t1, wA3, yA1);
            yA2 = fmaf(t1, wA4, yA2); yA3 = fmaf(t1, wA5, yA3);
            yB0 = fmaf(t1, wB2, yB0); yB1 = fmaf(t1, wB3, yB1);
            yB2 = fmaf(t1, wB4, yB2); yB3 = fmaf(t1, wB5, yB3);
            yA0 = fmaf(t2, wA3, yA0); yA1 = fmaf(t2, wA4, yA1);
            yA2 = fmaf(t2, wA5, yA2); yA3 = fmaf(t2, wA6, yA3);
            yB0 = fmaf(t2, wB3, yB0); yB1 = fmaf(t2, wB4, yB1);
            yB2 = fmaf(t2, wB5, yB2); yB3 = fmaf(t2, wB6, yB3);
            yA0 = fmaf(t3, wA4, yA0); yA1 = fmaf(t3, wA5, yA1);
            yA2 = fmaf(t3, wA6, yA2); yA3 = fmaf(t3, wA7, yA3);
            yB0 = fmaf(t3, wB4, yB0); yB1 = fmaf(t3, wB5, yB1);
            yB2 = fmaf(t3, wB6, yB2); yB3 = fmaf(t3, wB7, yB3);
            wA1 = wA5; wA2 = wA6; wA3 = wA7;
            wB1 = wB5; wB2 = wB6; wB3 = wB7;
        }

        // ---- tanh + masked accumulate (registers, no atomics) ----
        const int tA = base + aA;
        const int tB = base + aB;
        if (tA + 0 >= 0 && tA + 0 < ol) accA0 += fast_tanh(yA0);
        if (tA + 1 >= 0 && tA + 1 < ol) accA1 += fast_tanh(yA1);
        if (tA + 2 >= 0 && tA + 2 < ol) accA2 += fast_tanh(yA2);
        if (tA + 3 >= 0 && tA + 3 < ol) accA3 += fast_tanh(yA3);
        if (tB + 0 >= 0 && tB + 0 < ol) accB0 += fast_tanh(yB0);
        if (tB + 1 >= 0 && tB + 1 < ol) accB1 += fast_tanh(yB1);
        if (tB + 2 >= 0 && tB + 2 < ol) accB2 += fast_tanh(yB2);
        if (tB + 3 >= 0 && tB + 3 < ol) accB3 += fast_tanh(yB3);
    }

    // ---- coalesced stores ----
    const int oA = ow + aA;
    const int oB = ow + aB;
    if (oA + 3 < Dn) {
        *(float4*)&out[oA] = make_float4(accA0, accA1, accA2, accA3);
    } else {
        if (oA + 0 < Dn) out[oA + 0] = accA0;
        if (oA + 1 < Dn) out[oA + 1] = accA1;
        if (oA + 2 < Dn) out[oA + 2] = accA2;
        if (oA + 3 < Dn) out[oA + 3] = accA3;
    }
    if (oB + 3 < Dn) {
        *(float4*)&out[oB] = make_float4(accB0, accB1, accB2, accB3);
    } else {
        if (oB + 0 < Dn) out[oB + 0] = accB0;
        if (oB + 1 < Dn) out[oB + 1] = accB1;
        if (oB + 2 < Dn) out[oB + 2] = accB2;
        if (oB + 3 < Dn) out[oB + 3] = accB3;
    }
}

// ---------------- launcher ----------------
extern "C" void kernel_launch(void* const* d_in, const int* in_sizes, int n_in,
                              void* d_out, int out_size, void* d_ws, size_t ws_size,
                              hipStream_t stream) {
    const float* freq    = (const float*)d_in[0];
    const float* velo    = (const float*)d_in[1];
    const float* w1      = (const float*)d_in[2];
    const float* b1      = (const float*)d_in[3];
    const float* w2      = (const float*)d_in[4];
    const float* b2      = (const float*)d_in[5];
    const float* ws1     = (const float*)d_in[6];
    const float* bs1     = (const float*)d_in[7];
    const float* ws2     = (const float*)d_in[8];
    const float* bs2     = (const float*)d_in[9];
    const float* fir     = (const float*)d_in[10];
    const int*   starts  = (const int*)d_in[11];
    const int*   lengths = (const int*)d_in[12];

    const int N  = in_sizes[0];
    const int Dn = out_size;
    float* out = (float*)d_out;

    float* amps   = (float*)d_ws;
    int*   outlen = (int*)((char*)d_ws + (size_t)N * 8 * sizeof(float));
    float* veln   = (float*)((char*)d_ws + (size_t)N * 8 * sizeof(float) + (size_t)N * sizeof(int));

    params_k<<<(N + 255) / 256, 256, 0, stream>>>(
        freq, velo, w1, b1, w2, b2, ws1, bs1, ws2, bs2,
        starts, lengths, Dn, N, amps, outlen, veln);

    int n_tiles = (Dn + TO - 1) / TO;
    synth_gather_k<<<n_tiles, 128, 0, stream>>>(
        freq, starts, amps, outlen, veln, fir, out, Dn, N);
}